// Round 3
// baseline (766.928 us; speedup 1.0000x reference)
//
#include <hip/hip_runtime.h>
#include <math.h>

#define NN 16000
#define NE 256000
#define INV_SQRT_HD 0.35355339059327373f
#define LN_EPS 1e-5f
#define TPB_TILES 8   // tiles per persistent block; 2000 tiles / 250 blocks

typedef __attribute__((ext_vector_type(8))) short bf16x8;
typedef __attribute__((ext_vector_type(4))) float f32x4;

__device__ inline unsigned short f2bf(float x) {
    unsigned u = __float_as_uint(x);
    unsigned r = ((u >> 16) & 1u) + 0x7FFFu;
    return (unsigned short)((u + r) >> 16);
}
__device__ inline unsigned pack2(float lo, float hi) {
    return (unsigned)f2bf(lo) | ((unsigned)f2bf(hi) << 16);
}

// ---------------- prep: h->bf16, ew sigmoid, weight fragment packing ----------------
// New K' layout for GEMM1 (288): [feats 0..23][zero 24..31][hi 32..159][hj 160..287]
// w1p[((s*16+MT)*64+l)*8+j] = W1cat[row(k')][col=MT*16+(l&15)], k'=s*32+(l>>4)*8+j
//   row = k' (k'<24), none (24..31 -> 0), k'-8 (k'>=32)
__global__ __launch_bounds__(256) void prep_kernel(
    const float* __restrict__ h,
    const float* __restrict__ r_feat,
    const float* __restrict__ ewW, const float* __restrict__ ewB,
    const float* __restrict__ kW1, const float* __restrict__ vW1,
    const float* __restrict__ kW2, const float* __restrict__ vW2,
    unsigned short* __restrict__ h_bf, float* __restrict__ ew_pre,
    unsigned short* __restrict__ w1p, unsigned short* __restrict__ w2p)
{
    const int b = blockIdx.x, t = threadIdx.x;
    if (b < 1000) {
        const int gid = b * 256 + t;                  // 256000 threads x 8 elems
        const float4* hp = (const float4*)(h + (size_t)gid * 8);
        float4 a = hp[0], c = hp[1];
        ushort4 u0, u1;
        u0.x = f2bf(a.x); u0.y = f2bf(a.y); u0.z = f2bf(a.z); u0.w = f2bf(a.w);
        u1.x = f2bf(c.x); u1.y = f2bf(c.y); u1.z = f2bf(c.z); u1.w = f2bf(c.w);
        *(ushort4*)(h_bf + (size_t)gid * 8) = u0;
        *(ushort4*)(h_bf + (size_t)gid * 8 + 4) = u1;
    } else if (b < 2000) {
        const int e = (b - 1000) * 256 + t;
        const float* rp = r_feat + (size_t)e * 20;
        float z = ewB[0];
        #pragma unroll
        for (int i = 0; i < 20; ++i) z = fmaf(rp[i], ewW[i], z);
        ew_pre[e] = (1.f / (1.f + expf(-z))) * (1.f / 16.f);   // fold e_w and head-mean
    } else {
        const int idx = (b - 2000) * 256 + t;         // 360*256 = 92160
        if (idx < 73728) {
            int j = idx & 7, l = (idx >> 3) & 63, mtc = (idx >> 9) & 15, s = idx >> 13;
            int kp = s * 32 + (l >> 4) * 8 + j;
            int col = mtc * 16 + (l & 15);
            float v = 0.f;
            int row = (kp < 24) ? kp : ((kp >= 32) ? (kp - 8) : -1);
            if (row >= 0) v = (col < 128) ? kW1[(size_t)row * 128 + col]
                                          : vW1[(size_t)row * 128 + col - 128];
            w1p[idx] = f2bf(v);
        } else if (idx < 92160) {
            int i2 = idx - 73728;
            int j = i2 & 7, l = (i2 >> 3) & 63, sc = i2 >> 9;
            int ct = sc % 9, s2 = sc / 9;
            int k = s2 * 32 + (l >> 4) * 8 + j;
            float v = (ct < 8) ? kW2[(size_t)k * 128 + ct * 16 + (l & 15)]
                               : vW2[(size_t)k * 16 + (l & 15)];
            w2p[i2] = f2bf(v);
        }
    }
}

// ---------------- Kernel A: q = MLP(h) (fp32, small) ----------------
__global__ __launch_bounds__(256) void qmlp_kernel(
    const float* __restrict__ h,
    const float* __restrict__ W1, const float* __restrict__ B1,
    const float* __restrict__ G,  const float* __restrict__ BE,
    const float* __restrict__ W2, const float* __restrict__ B2,
    float* __restrict__ qout)
{
    __shared__ float xT[128][20];
    __shared__ float hT[128][20];
    __shared__ float ps1[16][65];
    __shared__ float ps2[16][65];
    __shared__ float mu_s[16], rs_s[16];

    const int t = threadIdx.x;
    const int nb = blockIdx.x * 16;

    {
        const int ln = t & 15;
        const int lc = (t >> 4) * 8;
        const float4* hp = (const float4*)(h + (size_t)(nb + ln) * 128 + lc);
        float4 a = hp[0], b = hp[1];
        xT[lc+0][ln] = a.x; xT[lc+1][ln] = a.y; xT[lc+2][ln] = a.z; xT[lc+3][ln] = a.w;
        xT[lc+4][ln] = b.x; xT[lc+5][ln] = b.y; xT[lc+6][ln] = b.z; xT[lc+7][ln] = b.w;
    }
    __syncthreads();

    const int n0 = (t & 3) * 4;
    const int jg = t >> 2;
    const int j0 = jg * 2;

    float acc[4][2];
    {
        float c0 = B1[j0], c1 = B1[j0+1];
        #pragma unroll
        for (int n = 0; n < 4; ++n) { acc[n][0] = c0; acc[n][1] = c1; }
    }
    #pragma unroll 4
    for (int i = 0; i < 128; ++i) {
        float4 x = *(const float4*)&xT[i][n0];
        float2 w = *(const float2*)(W1 + i*128 + j0);
        acc[0][0] = fmaf(x.x, w.x, acc[0][0]);
        acc[1][0] = fmaf(x.y, w.x, acc[1][0]);
        acc[2][0] = fmaf(x.z, w.x, acc[2][0]);
        acc[3][0] = fmaf(x.w, w.x, acc[3][0]);
        acc[0][1] = fmaf(x.x, w.y, acc[0][1]);
        acc[1][1] = fmaf(x.y, w.y, acc[1][1]);
        acc[2][1] = fmaf(x.z, w.y, acc[2][1]);
        acc[3][1] = fmaf(x.w, w.y, acc[3][1]);
    }
    #pragma unroll
    for (int n = 0; n < 4; ++n) {
        ps1[n0+n][jg] = acc[n][0] + acc[n][1];
        ps2[n0+n][jg] = acc[n][0]*acc[n][0] + acc[n][1]*acc[n][1];
    }
    __syncthreads();
    if (t < 16) {
        float s1 = 0.f, s2 = 0.f;
        for (int k = 0; k < 64; ++k) { s1 += ps1[t][k]; s2 += ps2[t][k]; }
        float mu = s1 * (1.f/128.f);
        float var = s2 * (1.f/128.f) - mu*mu;
        mu_s[t] = mu;
        rs_s[t] = rsqrtf(var + LN_EPS);
    }
    __syncthreads();
    #pragma unroll
    for (int c = 0; c < 2; ++c) {
        float gj = G[j0+c], bj = BE[j0+c];
        #pragma unroll
        for (int n = 0; n < 4; ++n) {
            float v = (acc[n][c] - mu_s[n0+n]) * rs_s[n0+n] * gj + bj;
            hT[j0+c][n0+n] = fmaxf(v, 0.f);
        }
    }
    __syncthreads();
    float a2[4][2];
    {
        float c0 = B2[j0], c1 = B2[j0+1];
        #pragma unroll
        for (int n = 0; n < 4; ++n) { a2[n][0] = c0; a2[n][1] = c1; }
    }
    #pragma unroll 4
    for (int i = 0; i < 128; ++i) {
        float4 x = *(const float4*)&hT[i][n0];
        float2 w = *(const float2*)(W2 + i*128 + j0);
        a2[0][0] = fmaf(x.x, w.x, a2[0][0]);
        a2[1][0] = fmaf(x.y, w.x, a2[1][0]);
        a2[2][0] = fmaf(x.z, w.x, a2[2][0]);
        a2[3][0] = fmaf(x.w, w.x, a2[3][0]);
        a2[0][1] = fmaf(x.x, w.y, a2[0][1]);
        a2[1][1] = fmaf(x.y, w.y, a2[1][1]);
        a2[2][1] = fmaf(x.z, w.y, a2[2][1]);
        a2[3][1] = fmaf(x.w, w.y, a2[3][1]);
    }
    #pragma unroll
    for (int n = 0; n < 4; ++n) {
        qout[(size_t)(nb+n0+n)*128 + j0]     = a2[n][0];
        qout[(size_t)(nb+n0+n)*128 + j0 + 1] = a2[n][1];
    }
}

// ------------- Kernel B: persistent MFMA edge kernel -------------
// 128 edges/tile, 1024 threads (16 waves: wm=w&3 col-blocks, wn=w>>2 edge-quarters),
// 8 tiles/block with reg-staged X prefetch (T14). 2 barriers/tile.
__device__ inline int4 load_chunk(int idx, int eb,
    const unsigned short* __restrict__ h_bf,
    const float* __restrict__ edge_feat, const float* __restrict__ r_feat,
    const int* __restrict__ eidx)
{
    const int e_loc = idx / 36, c = idx - e_loc * 36;
    const int e = eb + e_loc;
    if (c >= 4) {
        const int row = (c < 20) ? eidx[NE + e] : eidx[e];
        const int ofs = (c < 20) ? (c - 4) * 8 : (c - 20) * 8;
        return *(const int4*)(h_bf + (size_t)row * 128 + ofs);
    }
    if (c == 3) { int4 z; z.x = 0; z.y = 0; z.z = 0; z.w = 0; return z; }
    float4 lo, hi;
    if (c == 0) {
        lo = *(const float4*)(edge_feat + (size_t)e * 4);
        hi = *(const float4*)(r_feat + (size_t)e * 20);
    } else if (c == 1) {
        lo = *(const float4*)(r_feat + (size_t)e * 20 + 4);
        hi = *(const float4*)(r_feat + (size_t)e * 20 + 8);
    } else {
        lo = *(const float4*)(r_feat + (size_t)e * 20 + 12);
        hi = *(const float4*)(r_feat + (size_t)e * 20 + 16);
    }
    int4 r;
    r.x = pack2(lo.x, lo.y); r.y = pack2(lo.z, lo.w);
    r.z = pack2(hi.x, hi.y); r.w = pack2(hi.z, hi.w);
    return r;
}

__global__ __launch_bounds__(1024, 4) void edge_kernel(
    const unsigned short* __restrict__ h_bf,
    const float* __restrict__ edge_feat, const float* __restrict__ r_feat,
    const int*   __restrict__ eidx,
    const float* __restrict__ ew_pre,
    const float* __restrict__ kB1, const float* __restrict__ kG, const float* __restrict__ kBE,
    const float* __restrict__ vB1, const float* __restrict__ vG, const float* __restrict__ vBE,
    const float* __restrict__ kB2, const float* __restrict__ vB2,
    const unsigned short* __restrict__ w1p, const unsigned short* __restrict__ w2p,
    const float* __restrict__ q,
    float* __restrict__ ex_out, float* __restrict__ vw_out, float* __restrict__ denom)
{
    __shared__ __align__(16) unsigned char xs[128 * 640];   // X bf16 [128 e][stride 640B], XOR-swz
    __shared__ __align__(16) unsigned char hs[2 * 32768];   // hidden bf16 2 regions x [128 e][256B]
    __shared__ float2 lnb[4][128];
    __shared__ int    dst_s[2][128];
    __shared__ float  ew_s[2][128];
    __shared__ float  gb1[256];
    __shared__ float2 gbe[256];
    __shared__ float  gb2[144];

    const int t = threadIdx.x;
    const int w = t >> 6, l = t & 63;
    const int lrow = l & 15, lgrp = l >> 4;
    const int wm = w & 3, wn = w >> 2;

    if (t < 256) {
        gb1[t] = (t < 128) ? kB1[t] : vB1[t - 128];
        gbe[t] = make_float2((t < 128) ? kG[t] : vG[t - 128],
                             (t < 128) ? kBE[t] : vBE[t - 128]);
    } else if (t < 400) {
        int i = t - 256;
        gb2[i] = (i < 128) ? kB2[i] : vB2[i - 128];
    }

    const int tg0 = blockIdx.x * TPB_TILES;
    const int eb0 = tg0 * 128;

    // prologue: stage tile 0
    #pragma unroll
    for (int r = 0; r < 5; ++r) {
        int idx = r * 1024 + t;
        if (idx < 4608) {
            int4 v = load_chunk(idx, eb0, h_bf, edge_feat, r_feat, eidx);
            int e_loc = idx / 36, c = idx - e_loc * 36;
            *(int4*)(xs + e_loc * 640 + ((unsigned)(c * 16) ^ (unsigned)((e_loc & 7) << 4))) = v;
        }
    }
    if (t < 128) {
        dst_s[0][t] = eidx[NE + eb0 + t];
        ew_s[0][t]  = ew_pre[eb0 + t];
    }
    __syncthreads();

    // per-lane constants
    int ebyte[2], eswz[2];
    #pragma unroll
    for (int nt = 0; nt < 2; ++nt) {
        int el = wn * 32 + nt * 16 + lrow;
        ebyte[nt] = el * 640;
        eswz[nt]  = (el & 7) << 4;
    }

    for (int it = 0; it < TPB_TILES; ++it) {
        const int p = it & 1;
        const int eb = (tg0 + it) * 128;
        const bool hn = (it < TPB_TILES - 1);

        // ---- issue next-tile staging loads (registers) ----
        int4 stg0, stg1, stg2, stg3, stg4;
        int dstN = 0; float ewN = 0.f;
        if (hn) {
            const int ebn = eb + 128;
            stg0 = load_chunk(t,          ebn, h_bf, edge_feat, r_feat, eidx);
            stg1 = load_chunk(1024 + t,   ebn, h_bf, edge_feat, r_feat, eidx);
            stg2 = load_chunk(2048 + t,   ebn, h_bf, edge_feat, r_feat, eidx);
            stg3 = load_chunk(3072 + t,   ebn, h_bf, edge_feat, r_feat, eidx);
            if (t < 512) stg4 = load_chunk(4096 + t, ebn, h_bf, edge_feat, r_feat, eidx);
            if (t < 128) { dstN = eidx[NE + ebn + t]; ewN = ew_pre[ebn + t]; }
        }

        // ---- GEMM1: hiddenT[256][128e], K=288 (9 steps), reg double-buffered ----
        f32x4 acc1[4][2];
        #pragma unroll
        for (int mt = 0; mt < 4; ++mt) {
            const int cb = wm * 64 + mt * 16 + lgrp * 4;
            const float b0 = gb1[cb], b1 = gb1[cb+1], b2 = gb1[cb+2], b3 = gb1[cb+3];
            #pragma unroll
            for (int nt = 0; nt < 2; ++nt) {
                acc1[mt][nt][0] = b0; acc1[mt][nt][1] = b1;
                acc1[mt][nt][2] = b2; acc1[mt][nt][3] = b3;
            }
        }
        {
            bf16x8 aC[4], xC[2], aN[4], xN[2];
            #pragma unroll
            for (int mt = 0; mt < 4; ++mt)
                aC[mt] = *(const bf16x8*)(w1p + (size_t)(((0 * 16) + wm * 4 + mt) * 64 + l) * 8);
            #pragma unroll
            for (int nt = 0; nt < 2; ++nt)
                xC[nt] = *(const bf16x8*)(xs + ebyte[nt] + ((unsigned)(lgrp * 16) ^ (unsigned)eswz[nt]));
            #pragma unroll
            for (int s = 0; s < 9; ++s) {
                if (s < 8) {
                    #pragma unroll
                    for (int mt = 0; mt < 4; ++mt)
                        aN[mt] = *(const bf16x8*)(w1p + (size_t)((((s+1) * 16) + wm * 4 + mt) * 64 + l) * 8);
                    #pragma unroll
                    for (int nt = 0; nt < 2; ++nt)
                        xN[nt] = *(const bf16x8*)(xs + ebyte[nt] +
                                 ((unsigned)((s+1) * 64 + lgrp * 16) ^ (unsigned)eswz[nt]));
                }
                #pragma unroll
                for (int mt = 0; mt < 4; ++mt)
                    #pragma unroll
                    for (int nt = 0; nt < 2; ++nt)
                        acc1[mt][nt] = __builtin_amdgcn_mfma_f32_16x16x32_bf16(aC[mt], xC[nt], acc1[mt][nt], 0, 0, 0);
                #pragma unroll
                for (int mt = 0; mt < 4; ++mt) aC[mt] = aN[mt];
                #pragma unroll
                for (int nt = 0; nt < 2; ++nt) xC[nt] = xN[nt];
            }
        }

        // ---- LN partials (per edge, this wave's 64 cols) ----
        float2 myln[2];
        #pragma unroll
        for (int nt = 0; nt < 2; ++nt) {
            float p1 = 0.f, p2 = 0.f;
            #pragma unroll
            for (int mt = 0; mt < 4; ++mt)
                #pragma unroll
                for (int r = 0; r < 4; ++r) { float v = acc1[mt][nt][r]; p1 += v; p2 += v * v; }
            p1 += __shfl_xor(p1, 16); p2 += __shfl_xor(p2, 16);
            p1 += __shfl_xor(p1, 32); p2 += __shfl_xor(p2, 32);
            myln[nt] = make_float2(p1, p2);
            if (l < 16) lnb[wm][wn * 32 + nt * 16 + l] = myln[nt];
        }
        __syncthreads();   // B1

        // ---- normalize + ReLU + bf16 -> hidden LDS; write staged X(t+1) ----
        {
            const int region = wm >> 1;
            unsigned char* hb = hs + region * 32768;
            #pragma unroll
            for (int nt = 0; nt < 2; ++nt) {
                const int el = wn * 32 + nt * 16 + lrow;
                const float2 oth = lnb[wm ^ 1][el];
                const float s1 = myln[nt].x + oth.x, s2 = myln[nt].y + oth.y;
                const float mu = s1 * (1.f / 128.f);
                const float rs = rsqrtf(s2 * (1.f / 128.f) - mu * mu + LN_EPS);
                const unsigned swz = (unsigned)((el & 7) << 4);
                #pragma unroll
                for (int mt = 0; mt < 4; ++mt) {
                    const int cb = wm * 64 + mt * 16 + lgrp * 4;
                    const int kc = cb & 127;
                    const float2 g0 = gbe[cb], g1 = gbe[cb+1], g2 = gbe[cb+2], g3 = gbe[cb+3];
                    ushort4 u;
                    u.x = f2bf(fmaxf((acc1[mt][nt][0] - mu) * rs * g0.x + g0.y, 0.f));
                    u.y = f2bf(fmaxf((acc1[mt][nt][1] - mu) * rs * g1.x + g1.y, 0.f));
                    u.z = f2bf(fmaxf((acc1[mt][nt][2] - mu) * rs * g2.x + g2.y, 0.f));
                    u.w = f2bf(fmaxf((acc1[mt][nt][3] - mu) * rs * g3.x + g3.y, 0.f));
                    *(ushort4*)(hb + el * 256 + ((unsigned)(kc * 2) ^ swz)) = u;
                }
            }
        }
        if (hn) {
            #pragma unroll
            for (int r = 0; r < 5; ++r) {
                int idx = r * 1024 + t;
                if (idx < 4608) {
                    int4 v = (r == 0) ? stg0 : (r == 1) ? stg1 : (r == 2) ? stg2 : (r == 3) ? stg3 : stg4;
                    int e_loc = idx / 36, c = idx - e_loc * 36;
                    *(int4*)(xs + e_loc * 640 + ((unsigned)(c * 16) ^ (unsigned)((e_loc & 7) << 4))) = v;
                }
            }
            if (t < 128) { dst_s[p ^ 1][t] = dstN; ew_s[p ^ 1][t] = ewN; }
        }
        __syncthreads();   // B2

        // ---- GEMM2: kT[128][128e] + vT[16][128e], K=128 (4 steps) ----
        f32x4 acc2[2][2], accv;
        #pragma unroll
        for (int km = 0; km < 2; ++km) {
            const int c0 = (wm * 2 + km) * 16 + lgrp * 4;
            #pragma unroll
            for (int nt = 0; nt < 2; ++nt) {
                acc2[km][nt][0] = gb2[c0];     acc2[km][nt][1] = gb2[c0 + 1];
                acc2[km][nt][2] = gb2[c0 + 2]; acc2[km][nt][3] = gb2[c0 + 3];
            }
        }
        const int vel = wn * 32 + wm * 16 + lrow;   // valid when wm<2
        {
            const int cv = 128 + lgrp * 4;
            accv[0] = gb2[cv]; accv[1] = gb2[cv+1]; accv[2] = gb2[cv+2]; accv[3] = gb2[cv+3];
        }
        #pragma unroll
        for (int s2 = 0; s2 < 4; ++s2) {
            bf16x8 a0 = *(const bf16x8*)(w2p + (size_t)((s2 * 9 + wm * 2) * 64 + l) * 8);
            bf16x8 a1 = *(const bf16x8*)(w2p + (size_t)((s2 * 9 + wm * 2 + 1) * 64 + l) * 8);
            bf16x8 hbf[2];
            #pragma unroll
            for (int nt = 0; nt < 2; ++nt) {
                const int el = wn * 32 + nt * 16 + lrow;
                hbf[nt] = *(const bf16x8*)(hs + el * 256 +
                          ((unsigned)(s2 * 64 + lgrp * 16) ^ (unsigned)((el & 7) << 4)));
            }
            #pragma unroll
            for (int nt = 0; nt < 2; ++nt) {
                acc2[0][nt] = __builtin_amdgcn_mfma_f32_16x16x32_bf16(a0, hbf[nt], acc2[0][nt], 0, 0, 0);
                acc2[1][nt] = __builtin_amdgcn_mfma_f32_16x16x32_bf16(a1, hbf[nt], acc2[1][nt], 0, 0, 0);
            }
            if (wm < 2) {
                bf16x8 av = *(const bf16x8*)(w2p + (size_t)((s2 * 9 + 8) * 64 + l) * 8);
                bf16x8 hv = *(const bf16x8*)(hs + 32768 + vel * 256 +
                            ((unsigned)(s2 * 64 + lgrp * 16) ^ (unsigned)((vel & 7) << 4)));
                accv = __builtin_amdgcn_mfma_f32_16x16x32_bf16(av, hv, accv, 0, 0, 0);
            }
        }

        // ---- v output ----
        if (wm < 2) {
            const float sc = ew_s[p][vel];
            float4 vo;
            vo.x = accv[0] * sc; vo.y = accv[1] * sc; vo.z = accv[2] * sc; vo.w = accv[3] * sc;
            *(float4*)(vw_out + (size_t)(eb + vel) * 16 + lgrp * 4) = vo;
        }

        // ---- scores + exp + denom atomics ----
        #pragma unroll
        for (int km = 0; km < 2; ++km) {
            #pragma unroll
            for (int nt = 0; nt < 2; ++nt) {
                const int el = wn * 32 + nt * 16 + lrow;
                const int c0 = (wm * 2 + km) * 16 + lgrp * 4;
                const int dst = dst_s[p][el];
                const float4 qv = *(const float4*)(q + (size_t)dst * 128 + c0);
                float sp = acc2[km][nt][0] * qv.x + acc2[km][nt][1] * qv.y
                         + acc2[km][nt][2] * qv.z + acc2[km][nt][3] * qv.w;
                sp += __shfl_xor(sp, 16);
                if ((l & 16) == 0) {
                    const float exv = expf(sp * INV_SQRT_HD);
                    const int hh = (wm * 2 + km) * 2 + (lgrp >> 1);
                    ex_out[(size_t)(eb + el) * 16 + hh] = exv;
                    atomicAdd(&denom[(size_t)dst * 16 + hh], exv);
                }
            }
        }
    }
}

// ------------- Kernel C: alpha = ex/denom, scatter out += sum_h(alpha*vw)*rel_x -------------
__global__ __launch_bounds__(256) void finalize_kernel(
    const int* __restrict__ eidx, const float* __restrict__ relx,
    const float* __restrict__ exb, const float* __restrict__ vwb,
    const float* __restrict__ den, float* __restrict__ out)
{
    const int e = blockIdx.x * 256 + threadIdx.x;
    const int dst = eidx[NE + e];
    const float4* ex4 = (const float4*)(exb + (size_t)e*16);
    const float4* vw4 = (const float4*)(vwb + (size_t)e*16);
    const float4* dn4 = (const float4*)(den + (size_t)dst*16);
    float s = 0.f;
    #pragma unroll
    for (int k = 0; k < 4; ++k) {
        float4 a = ex4[k], b = vw4[k], d = dn4[k];
        s += (a.x/d.x)*b.x + (a.y/d.y)*b.y + (a.z/d.z)*b.z + (a.w/d.w)*b.w;
    }
    float r0 = relx[(size_t)e*3+0], r1 = relx[(size_t)e*3+1], r2 = relx[(size_t)e*3+2];
    atomicAdd(&out[(size_t)dst*3+0], s*r0);
    atomicAdd(&out[(size_t)dst*3+1], s*r1);
    atomicAdd(&out[(size_t)dst*3+2], s*r2);
}

extern "C" void kernel_launch(void* const* d_in, const int* in_sizes, int n_in,
                              void* d_out, int out_size, void* d_ws, size_t ws_size,
                              hipStream_t stream) {
    const float* h         = (const float*)d_in[0];
    const float* rel_x     = (const float*)d_in[1];
    const float* r_feat    = (const float*)d_in[2];
    const float* edge_feat = (const float*)d_in[3];
    const int*   eidx      = (const int*)  d_in[4];
    const float* kW1 = (const float*)d_in[5];
    const float* kB1 = (const float*)d_in[6];
    const float* kG  = (const float*)d_in[7];
    const float* kBE = (const float*)d_in[8];
    const float* kW2 = (const float*)d_in[9];
    const float* kB2 = (const float*)d_in[10];
    const float* vW1 = (const float*)d_in[11];
    const float* vB1 = (const float*)d_in[12];
    const float* vG  = (const float*)d_in[13];
    const float* vBE = (const float*)d_in[14];
    const float* vW2 = (const float*)d_in[15];
    const float* vB2 = (const float*)d_in[16];
    const float* qW1 = (const float*)d_in[17];
    const float* qB1 = (const float*)d_in[18];
    const float* qG  = (const float*)d_in[19];
    const float* qBE = (const float*)d_in[20];
    const float* qW2 = (const float*)d_in[21];
    const float* qB2 = (const float*)d_in[22];
    const float* ewW = (const float*)d_in[23];
    const float* ewB = (const float*)d_in[24];

    float* ws   = (float*)d_ws;
    float* qbuf = ws;                             // N*128
    float* exb  = qbuf + (size_t)NN*128;          // E*16
    float* vwb  = exb + (size_t)NE*16;            // E*16
    float* den  = vwb + (size_t)NE*16;            // N*16
    float* ewp  = den + (size_t)NN*16;            // E
    unsigned short* w1p  = (unsigned short*)(ewp + (size_t)NE);   // 73728
    unsigned short* w2p  = w1p + 73728;                           // 18432
    unsigned short* h_bf = w2p + 18432;                           // N*128
    float* outf = (float*)d_out;

    hipMemsetAsync(den, 0, (size_t)NN*16*sizeof(float), stream);
    hipMemsetAsync(outf, 0, (size_t)NN*3*sizeof(float), stream);

    prep_kernel<<<2360, 256, 0, stream>>>(h, r_feat, ewW, ewB, kW1, vW1, kW2, vW2,
                                          h_bf, ewp, w1p, w2p);
    qmlp_kernel<<<NN/16, 256, 0, stream>>>(h, qW1, qB1, qG, qBE, qW2, qB2, qbuf);
    edge_kernel<<<NE/128/TPB_TILES, 1024, 0, stream>>>(h_bf, edge_feat, r_feat, eidx, ewp,
                                           kB1, kG, kBE, vB1, vG, vBE,
                                           kB2, vB2, w1p, w2p, qbuf,
                                           exb, vwb, den);
    finalize_kernel<<<NE/256, 256, 0, stream>>>(eidx, rel_x, exb, vwb, den, outf);
}

// Round 4
// 303.080 us; speedup vs baseline: 2.5305x; 2.5305x over previous
//
#include <hip/hip_runtime.h>
#include <math.h>

#define NN 16000
#define NE 256000
#define INV_SQRT_HD 0.35355339059327373f
#define LN_EPS 1e-5f

typedef __attribute__((ext_vector_type(8))) short bf16x8;
typedef __attribute__((ext_vector_type(4))) float f32x4;

__device__ inline unsigned short f2bf(float x) {
    unsigned u = __float_as_uint(x);
    unsigned r = ((u >> 16) & 1u) + 0x7FFFu;
    return (unsigned short)((u + r) >> 16);
}

// ---------------- prep: h->bf16, feats pack, ew sigmoid, weight fragment packing ----------------
// K' layout for GEMM1 (288): [feats 0..23][zero 24..31][hi 32..159][hj 160..287]
// w1p[((s*16+MT)*64+l)*8+j] = W1cat[row(k')][col=MT*16+(l&15)], k'=s*32+(l>>4)*8+j
//   row = k' (k'<24), zero (24..31), k'-8 (k'>=32)
__global__ __launch_bounds__(256) void prep_kernel(
    const float* __restrict__ h,
    const float* __restrict__ r_feat,
    const float* __restrict__ edge_feat,
    const float* __restrict__ ewW, const float* __restrict__ ewB,
    const float* __restrict__ kW1, const float* __restrict__ vW1,
    const float* __restrict__ kW2, const float* __restrict__ vW2,
    unsigned short* __restrict__ h_bf, unsigned short* __restrict__ feats_bf,
    float* __restrict__ ew_pre,
    unsigned short* __restrict__ w1p, unsigned short* __restrict__ w2p)
{
    const int b = blockIdx.x, t = threadIdx.x;
    if (b < 1000) {
        const int gid = b * 256 + t;                  // 256000 threads x 8 elems
        const float4* hp = (const float4*)(h + (size_t)gid * 8);
        float4 a = hp[0], c = hp[1];
        ushort4 u0, u1;
        u0.x = f2bf(a.x); u0.y = f2bf(a.y); u0.z = f2bf(a.z); u0.w = f2bf(a.w);
        u1.x = f2bf(c.x); u1.y = f2bf(c.y); u1.z = f2bf(c.z); u1.w = f2bf(c.w);
        *(ushort4*)(h_bf + (size_t)gid * 8) = u0;
        *(ushort4*)(h_bf + (size_t)gid * 8 + 4) = u1;
    } else if (b < 2000) {
        const int e = (b - 1000) * 256 + t;
        float4 ef = *(const float4*)(edge_feat + (size_t)e * 4);
        float rf[20];
        #pragma unroll
        for (int i = 0; i < 5; ++i)
            *(float4*)&rf[i * 4] = *(const float4*)(r_feat + (size_t)e * 20 + i * 4);
        float z = ewB[0];
        #pragma unroll
        for (int i = 0; i < 20; ++i) z = fmaf(rf[i], ewW[i], z);
        ew_pre[e] = (1.f / (1.f + expf(-z))) * (1.f / 16.f);   // fold e_w and head-mean
        unsigned short fb[32];
        fb[0] = f2bf(ef.x); fb[1] = f2bf(ef.y); fb[2] = f2bf(ef.z); fb[3] = f2bf(ef.w);
        #pragma unroll
        for (int i = 0; i < 20; ++i) fb[4 + i] = f2bf(rf[i]);
        #pragma unroll
        for (int i = 24; i < 32; ++i) fb[i] = 0;
        #pragma unroll
        for (int i = 0; i < 4; ++i)
            *(int4*)(feats_bf + (size_t)e * 32 + i * 8) = *(int4*)&fb[i * 8];
    } else {
        const int idx = (b - 2000) * 256 + t;         // 360*256 = 92160
        if (idx < 73728) {
            int j = idx & 7, l = (idx >> 3) & 63, mtc = (idx >> 9) & 15, s = idx >> 13;
            int kp = s * 32 + (l >> 4) * 8 + j;
            int col = mtc * 16 + (l & 15);
            float v = 0.f;
            int row = (kp < 24) ? kp : ((kp >= 32) ? (kp - 8) : -1);
            if (row >= 0) v = (col < 128) ? kW1[(size_t)row * 128 + col]
                                          : vW1[(size_t)row * 128 + col - 128];
            w1p[idx] = f2bf(v);
        } else if (idx < 92160) {
            int i2 = idx - 73728;
            int j = i2 & 7, l = (i2 >> 3) & 63, sc = i2 >> 9;
            int ct = sc % 9, s2 = sc / 9;
            int k = s2 * 32 + (l >> 4) * 8 + j;
            float v = (ct < 8) ? kW2[(size_t)k * 128 + ct * 16 + (l & 15)]
                               : vW2[(size_t)k * 16 + (l & 15)];
            w2p[i2] = f2bf(v);
        }
    }
}

// ---------------- Kernel A: q = MLP(h) (fp32, small) ----------------
__global__ __launch_bounds__(256) void qmlp_kernel(
    const float* __restrict__ h,
    const float* __restrict__ W1, const float* __restrict__ B1,
    const float* __restrict__ G,  const float* __restrict__ BE,
    const float* __restrict__ W2, const float* __restrict__ B2,
    float* __restrict__ qout)
{
    __shared__ float xT[128][20];
    __shared__ float hT[128][20];
    __shared__ float ps1[16][65];
    __shared__ float ps2[16][65];
    __shared__ float mu_s[16], rs_s[16];

    const int t = threadIdx.x;
    const int nb = blockIdx.x * 16;

    {
        const int ln = t & 15;
        const int lc = (t >> 4) * 8;
        const float4* hp = (const float4*)(h + (size_t)(nb + ln) * 128 + lc);
        float4 a = hp[0], b = hp[1];
        xT[lc+0][ln] = a.x; xT[lc+1][ln] = a.y; xT[lc+2][ln] = a.z; xT[lc+3][ln] = a.w;
        xT[lc+4][ln] = b.x; xT[lc+5][ln] = b.y; xT[lc+6][ln] = b.z; xT[lc+7][ln] = b.w;
    }
    __syncthreads();

    const int n0 = (t & 3) * 4;
    const int jg = t >> 2;
    const int j0 = jg * 2;

    float acc[4][2];
    {
        float c0 = B1[j0], c1 = B1[j0+1];
        #pragma unroll
        for (int n = 0; n < 4; ++n) { acc[n][0] = c0; acc[n][1] = c1; }
    }
    #pragma unroll 4
    for (int i = 0; i < 128; ++i) {
        float4 x = *(const float4*)&xT[i][n0];
        float2 w = *(const float2*)(W1 + i*128 + j0);
        acc[0][0] = fmaf(x.x, w.x, acc[0][0]);
        acc[1][0] = fmaf(x.y, w.x, acc[1][0]);
        acc[2][0] = fmaf(x.z, w.x, acc[2][0]);
        acc[3][0] = fmaf(x.w, w.x, acc[3][0]);
        acc[0][1] = fmaf(x.x, w.y, acc[0][1]);
        acc[1][1] = fmaf(x.y, w.y, acc[1][1]);
        acc[2][1] = fmaf(x.z, w.y, acc[2][1]);
        acc[3][1] = fmaf(x.w, w.y, acc[3][1]);
    }
    #pragma unroll
    for (int n = 0; n < 4; ++n) {
        ps1[n0+n][jg] = acc[n][0] + acc[n][1];
        ps2[n0+n][jg] = acc[n][0]*acc[n][0] + acc[n][1]*acc[n][1];
    }
    __syncthreads();
    if (t < 16) {
        float s1 = 0.f, s2 = 0.f;
        for (int k = 0; k < 64; ++k) { s1 += ps1[t][k]; s2 += ps2[t][k]; }
        float mu = s1 * (1.f/128.f);
        float var = s2 * (1.f/128.f) - mu*mu;
        mu_s[t] = mu;
        rs_s[t] = rsqrtf(var + LN_EPS);
    }
    __syncthreads();
    #pragma unroll
    for (int c = 0; c < 2; ++c) {
        float gj = G[j0+c], bj = BE[j0+c];
        #pragma unroll
        for (int n = 0; n < 4; ++n) {
            float v = (acc[n][c] - mu_s[n0+n]) * rs_s[n0+n] * gj + bj;
            hT[j0+c][n0+n] = fmaxf(v, 0.f);
        }
    }
    __syncthreads();
    float a2[4][2];
    {
        float c0 = B2[j0], c1 = B2[j0+1];
        #pragma unroll
        for (int n = 0; n < 4; ++n) { a2[n][0] = c0; a2[n][1] = c1; }
    }
    #pragma unroll 4
    for (int i = 0; i < 128; ++i) {
        float4 x = *(const float4*)&hT[i][n0];
        float2 w = *(const float2*)(W2 + i*128 + j0);
        a2[0][0] = fmaf(x.x, w.x, a2[0][0]);
        a2[1][0] = fmaf(x.y, w.x, a2[1][0]);
        a2[2][0] = fmaf(x.z, w.x, a2[2][0]);
        a2[3][0] = fmaf(x.w, w.x, a2[3][0]);
        a2[0][1] = fmaf(x.x, w.y, a2[0][1]);
        a2[1][1] = fmaf(x.y, w.y, a2[1][1]);
        a2[2][1] = fmaf(x.z, w.y, a2[2][1]);
        a2[3][1] = fmaf(x.w, w.y, a2[3][1]);
    }
    #pragma unroll
    for (int n = 0; n < 4; ++n) {
        qout[(size_t)(nb+n0+n)*128 + j0]     = a2[n][0];
        qout[(size_t)(nb+n0+n)*128 + j0 + 1] = a2[n][1];
    }
}

// ------------- Kernel B: MFMA edge kernel, direct-global B-fragments -------------
// 64 edges/block, 256 threads (4 waves). Wave w owns output cols [w*64, w*64+64).
// GEMM1 B (X) gathered per-lane 16B directly from feats_bf/h_bf (no X LDS).
__global__ __launch_bounds__(256, 2) void edge_kernel(
    const unsigned short* __restrict__ h_bf,
    const unsigned short* __restrict__ feats_bf,
    const int*   __restrict__ eidx,
    const float* __restrict__ ew_pre,
    const float* __restrict__ kB1, const float* __restrict__ kG, const float* __restrict__ kBE,
    const float* __restrict__ vB1, const float* __restrict__ vG, const float* __restrict__ vBE,
    const float* __restrict__ kB2, const float* __restrict__ vB2,
    const unsigned short* __restrict__ w1p, const unsigned short* __restrict__ w2p,
    const float* __restrict__ q,
    float* __restrict__ ex_out, float* __restrict__ vw_out, float* __restrict__ denom)
{
    __shared__ __align__(16) unsigned char hs[32768];  // hidden bf16, 2 regions x [64e][256B], XOR-swz
    __shared__ float2 lnb[4][64];
    __shared__ float  gb1[256];
    __shared__ float2 gbe[256];
    __shared__ float  gb2[144];
    __shared__ int    dst_sh[64];
    __shared__ float  ew_s[64];

    const int t = threadIdx.x;
    const int eb = blockIdx.x * 64;
    const int w = t >> 6, l = t & 63, lrow = l & 15, lgrp = l >> 4;

    gb1[t] = (t < 128) ? kB1[t] : vB1[t - 128];
    gbe[t] = make_float2((t < 128) ? kG[t] : vG[t - 128],
                         (t < 128) ? kBE[t] : vBE[t - 128]);
    if (t < 144) gb2[t] = (t < 128) ? kB2[t] : vB2[t - 128];
    if (t < 64) {
        dst_sh[t] = eidx[NE + eb + t];
        ew_s[t]   = ew_pre[eb + t];
    }

    // per-lane B pointers (edge el = nt*16 + lrow; 8 consecutive k at lgrp*8)
    const unsigned short* pF[4];
    const unsigned short* pD[4];
    const unsigned short* pS[4];
    #pragma unroll
    for (int nt = 0; nt < 4; ++nt) {
        const int e = eb + nt * 16 + lrow;
        pF[nt] = feats_bf + (size_t)e * 32 + lgrp * 8;
        pD[nt] = h_bf + (size_t)eidx[NE + e] * 128 + lgrp * 8;
        pS[nt] = h_bf + (size_t)eidx[e] * 128 + lgrp * 8;
    }
    __syncthreads();

    // ---- GEMM1: hiddenT[256 cols][64 e], K'=288 (9 steps), reg double-buffered ----
    f32x4 acc1[4][4];
    #pragma unroll
    for (int mt = 0; mt < 4; ++mt) {
        const int cb = w * 64 + mt * 16 + lgrp * 4;
        const float b0 = gb1[cb], b1 = gb1[cb+1], b2 = gb1[cb+2], b3 = gb1[cb+3];
        #pragma unroll
        for (int nt = 0; nt < 4; ++nt) {
            acc1[mt][nt][0] = b0; acc1[mt][nt][1] = b1;
            acc1[mt][nt][2] = b2; acc1[mt][nt][3] = b3;
        }
    }
    {
        bf16x8 aC[4], bC[4];
        #pragma unroll
        for (int mt = 0; mt < 4; ++mt)
            aC[mt] = *(const bf16x8*)(w1p + (size_t)((w * 4 + mt) * 64 + l) * 8);
        #pragma unroll
        for (int nt = 0; nt < 4; ++nt)
            bC[nt] = *(const bf16x8*)pF[nt];
        #pragma unroll
        for (int s = 0; s < 9; ++s) {
            bf16x8 aN[4], bN[4];
            if (s < 8) {
                #pragma unroll
                for (int mt = 0; mt < 4; ++mt)
                    aN[mt] = *(const bf16x8*)(w1p + (size_t)(((s + 1) * 16 + w * 4 + mt) * 64 + l) * 8);
                #pragma unroll
                for (int nt = 0; nt < 4; ++nt)
                    bN[nt] = (s + 1 <= 4) ? *(const bf16x8*)(pD[nt] + s * 32)
                                          : *(const bf16x8*)(pS[nt] + (s - 4) * 32);
            }
            #pragma unroll
            for (int mt = 0; mt < 4; ++mt)
                #pragma unroll
                for (int nt = 0; nt < 4; ++nt)
                    acc1[mt][nt] = __builtin_amdgcn_mfma_f32_16x16x32_bf16(aC[mt], bC[nt], acc1[mt][nt], 0, 0, 0);
            #pragma unroll
            for (int mt = 0; mt < 4; ++mt) aC[mt] = aN[mt];
            #pragma unroll
            for (int nt = 0; nt < 4; ++nt) bC[nt] = bN[nt];
        }
    }

    // ---- LN partials (per edge, this wave's 64 cols) ----
    float2 myln[4];
    #pragma unroll
    for (int nt = 0; nt < 4; ++nt) {
        float p1 = 0.f, p2 = 0.f;
        #pragma unroll
        for (int mt = 0; mt < 4; ++mt)
            #pragma unroll
            for (int r = 0; r < 4; ++r) { float v = acc1[mt][nt][r]; p1 += v; p2 += v * v; }
        p1 += __shfl_xor(p1, 16); p2 += __shfl_xor(p2, 16);
        p1 += __shfl_xor(p1, 32); p2 += __shfl_xor(p2, 32);
        myln[nt] = make_float2(p1, p2);
        if (l < 16) lnb[w][nt * 16 + l] = myln[nt];
    }
    __syncthreads();   // B1

    // ---- normalize + ReLU + bf16 -> hidden LDS (row-major [e][128cols], XOR-swz) ----
    {
        const int region = w >> 1;
        unsigned char* hb = hs + region * 16384;
        #pragma unroll
        for (int nt = 0; nt < 4; ++nt) {
            const int el = nt * 16 + lrow;
            const float2 oth = lnb[w ^ 1][el];
            const float s1 = myln[nt].x + oth.x, s2 = myln[nt].y + oth.y;
            const float mu = s1 * (1.f / 128.f);
            const float rs = rsqrtf(s2 * (1.f / 128.f) - mu * mu + LN_EPS);
            const unsigned swz = (unsigned)((el & 7) << 4);
            #pragma unroll
            for (int mt = 0; mt < 4; ++mt) {
                const int cb = w * 64 + mt * 16 + lgrp * 4;
                const int kc = cb & 127;
                const float2 g0 = gbe[cb], g1 = gbe[cb+1], g2 = gbe[cb+2], g3 = gbe[cb+3];
                ushort4 u;
                u.x = f2bf(fmaxf((acc1[mt][nt][0] - mu) * rs * g0.x + g0.y, 0.f));
                u.y = f2bf(fmaxf((acc1[mt][nt][1] - mu) * rs * g1.x + g1.y, 0.f));
                u.z = f2bf(fmaxf((acc1[mt][nt][2] - mu) * rs * g2.x + g2.y, 0.f));
                u.w = f2bf(fmaxf((acc1[mt][nt][3] - mu) * rs * g3.x + g3.y, 0.f));
                *(ushort4*)(hb + el * 256 + ((unsigned)(kc * 2) ^ swz)) = u;
            }
        }
    }
    __syncthreads();   // B2

    // ---- GEMM2: kT[128][64e] + vT[16][64e], K=128 (4 steps), A prefetched ----
    f32x4 acc2[2][4], accv;
    #pragma unroll
    for (int km = 0; km < 2; ++km) {
        const int c0 = (w * 2 + km) * 16 + lgrp * 4;
        #pragma unroll
        for (int nt = 0; nt < 4; ++nt) {
            acc2[km][nt][0] = gb2[c0];     acc2[km][nt][1] = gb2[c0 + 1];
            acc2[km][nt][2] = gb2[c0 + 2]; acc2[km][nt][3] = gb2[c0 + 3];
        }
    }
    const int vel = w * 16 + lrow;
    {
        const int cv = 128 + lgrp * 4;
        accv[0] = gb2[cv]; accv[1] = gb2[cv+1]; accv[2] = gb2[cv+2]; accv[3] = gb2[cv+3];
    }
    {
        bf16x8 a0C = *(const bf16x8*)(w2p + (size_t)((w * 2) * 64 + l) * 8);
        bf16x8 a1C = *(const bf16x8*)(w2p + (size_t)((w * 2 + 1) * 64 + l) * 8);
        bf16x8 avC = *(const bf16x8*)(w2p + (size_t)(8 * 64 + l) * 8);
        #pragma unroll
        for (int s2 = 0; s2 < 4; ++s2) {
            bf16x8 a0N, a1N, avN;
            if (s2 < 3) {
                a0N = *(const bf16x8*)(w2p + (size_t)(((s2+1) * 9 + w * 2) * 64 + l) * 8);
                a1N = *(const bf16x8*)(w2p + (size_t)(((s2+1) * 9 + w * 2 + 1) * 64 + l) * 8);
                avN = *(const bf16x8*)(w2p + (size_t)(((s2+1) * 9 + 8) * 64 + l) * 8);
            }
            const unsigned kb = (unsigned)(s2 * 64 + lgrp * 16);
            bf16x8 hbf[4];
            #pragma unroll
            for (int nt = 0; nt < 4; ++nt) {
                const int el = nt * 16 + lrow;
                hbf[nt] = *(const bf16x8*)(hs + el * 256 + (kb ^ (unsigned)((el & 7) << 4)));
            }
            {
                bf16x8 hv = *(const bf16x8*)(hs + 16384 + vel * 256 + (kb ^ (unsigned)((vel & 7) << 4)));
                accv = __builtin_amdgcn_mfma_f32_16x16x32_bf16(avC, hv, accv, 0, 0, 0);
            }
            #pragma unroll
            for (int nt = 0; nt < 4; ++nt) {
                acc2[0][nt] = __builtin_amdgcn_mfma_f32_16x16x32_bf16(a0C, hbf[nt], acc2[0][nt], 0, 0, 0);
                acc2[1][nt] = __builtin_amdgcn_mfma_f32_16x16x32_bf16(a1C, hbf[nt], acc2[1][nt], 0, 0, 0);
            }
            a0C = a0N; a1C = a1N; avC = avN;
        }
    }

    // ---- v output: lane holds v[e=vel][head=lgrp*4+r] ----
    {
        const float sc = ew_s[vel];
        float4 vo;
        vo.x = accv[0] * sc; vo.y = accv[1] * sc; vo.z = accv[2] * sc; vo.w = accv[3] * sc;
        *(float4*)(vw_out + (size_t)(eb + vel) * 16 + lgrp * 4) = vo;
    }

    // ---- scores + exp + denom atomics (q read direct from global) ----
    #pragma unroll
    for (int km = 0; km < 2; ++km) {
        #pragma unroll
        for (int nt = 0; nt < 4; ++nt) {
            const int el = nt * 16 + lrow;
            const int c0 = (w * 2 + km) * 16 + lgrp * 4;
            const int dst = dst_sh[el];
            const float4 qv = *(const float4*)(q + (size_t)dst * 128 + c0);
            float sp = acc2[km][nt][0] * qv.x + acc2[km][nt][1] * qv.y
                     + acc2[km][nt][2] * qv.z + acc2[km][nt][3] * qv.w;
            sp += __shfl_xor(sp, 16);
            if ((l & 16) == 0) {
                const float exv = expf(sp * INV_SQRT_HD);
                const int hh = (w * 2 + km) * 2 + (lgrp >> 1);
                ex_out[(size_t)(eb + el) * 16 + hh] = exv;
                atomicAdd(&denom[(size_t)dst * 16 + hh], exv);
            }
        }
    }
}

// ------------- Kernel C: alpha = ex/denom, scatter out += sum_h(alpha*vw)*rel_x -------------
__global__ __launch_bounds__(256) void finalize_kernel(
    const int* __restrict__ eidx, const float* __restrict__ relx,
    const float* __restrict__ exb, const float* __restrict__ vwb,
    const float* __restrict__ den, float* __restrict__ out)
{
    const int e = blockIdx.x * 256 + threadIdx.x;
    const int dst = eidx[NE + e];
    const float4* ex4 = (const float4*)(exb + (size_t)e*16);
    const float4* vw4 = (const float4*)(vwb + (size_t)e*16);
    const float4* dn4 = (const float4*)(den + (size_t)dst*16);
    float s = 0.f;
    #pragma unroll
    for (int k = 0; k < 4; ++k) {
        float4 a = ex4[k], b = vw4[k], d = dn4[k];
        s += (a.x/d.x)*b.x + (a.y/d.y)*b.y + (a.z/d.z)*b.z + (a.w/d.w)*b.w;
    }
    float r0 = relx[(size_t)e*3+0], r1 = relx[(size_t)e*3+1], r2 = relx[(size_t)e*3+2];
    atomicAdd(&out[(size_t)dst*3+0], s*r0);
    atomicAdd(&out[(size_t)dst*3+1], s*r1);
    atomicAdd(&out[(size_t)dst*3+2], s*r2);
}

extern "C" void kernel_launch(void* const* d_in, const int* in_sizes, int n_in,
                              void* d_out, int out_size, void* d_ws, size_t ws_size,
                              hipStream_t stream) {
    const float* h         = (const float*)d_in[0];
    const float* rel_x     = (const float*)d_in[1];
    const float* r_feat    = (const float*)d_in[2];
    const float* edge_feat = (const float*)d_in[3];
    const int*   eidx      = (const int*)  d_in[4];
    const float* kW1 = (const float*)d_in[5];
    const float* kB1 = (const float*)d_in[6];
    const float* kG  = (const float*)d_in[7];
    const float* kBE = (const float*)d_in[8];
    const float* kW2 = (const float*)d_in[9];
    const float* kB2 = (const float*)d_in[10];
    const float* vW1 = (const float*)d_in[11];
    const float* vB1 = (const float*)d_in[12];
    const float* vG  = (const float*)d_in[13];
    const float* vBE = (const float*)d_in[14];
    const float* vW2 = (const float*)d_in[15];
    const float* vB2 = (const float*)d_in[16];
    const float* qW1 = (const float*)d_in[17];
    const float* qB1 = (const float*)d_in[18];
    const float* qG  = (const float*)d_in[19];
    const float* qBE = (const float*)d_in[20];
    const float* qW2 = (const float*)d_in[21];
    const float* qB2 = (const float*)d_in[22];
    const float* ewW = (const float*)d_in[23];
    const float* ewB = (const float*)d_in[24];

    float* ws   = (float*)d_ws;
    float* qbuf = ws;                             // N*128
    float* exb  = qbuf + (size_t)NN*128;          // E*16
    float* vwb  = exb + (size_t)NE*16;            // E*16
    float* den  = vwb + (size_t)NE*16;            // N*16
    float* ewp  = den + (size_t)NN*16;            // E
    unsigned short* w1p  = (unsigned short*)(ewp + (size_t)NE);   // 73728
    unsigned short* w2p  = w1p + 73728;                           // 18432
    unsigned short* h_bf = w2p + 18432;                           // N*128
    unsigned short* feats_bf = h_bf + (size_t)NN*128;             // E*32
    float* outf = (float*)d_out;

    hipMemsetAsync(den, 0, (size_t)NN*16*sizeof(float), stream);
    hipMemsetAsync(outf, 0, (size_t)NN*3*sizeof(float), stream);

    prep_kernel<<<2360, 256, 0, stream>>>(h, r_feat, edge_feat, ewW, ewB,
                                          kW1, vW1, kW2, vW2,
                                          h_bf, feats_bf, ewp, w1p, w2p);
    qmlp_kernel<<<NN/16, 256, 0, stream>>>(h, qW1, qB1, qG, qBE, qW2, qB2, qbuf);
    edge_kernel<<<NE/64, 256, 0, stream>>>(h_bf, feats_bf, eidx, ewp,
                                           kB1, kG, kBE, vB1, vG, vBE,
                                           kB2, vB2, w1p, w2p, qbuf,
                                           exb, vwb, den);
    finalize_kernel<<<NE/256, 256, 0, stream>>>(eidx, rel_x, exb, vwb, den, outf);
}

// Round 5
// 274.688 us; speedup vs baseline: 2.7920x; 1.1034x over previous
//
#include <hip/hip_runtime.h>
#include <math.h>

#define NN 16000
#define NE 256000
#define INV_SQRT_HD 0.35355339059327373f
#define LN_EPS 1e-5f

typedef __attribute__((ext_vector_type(8))) short bf16x8;
typedef __attribute__((ext_vector_type(4))) float f32x4;

__device__ inline unsigned short f2bf(float x) {
    unsigned u = __float_as_uint(x);
    unsigned r = ((u >> 16) & 1u) + 0x7FFFu;
    return (unsigned short)((u + r) >> 16);
}

// ---------------- prep: h->bf16, feats pack, ew sigmoid, weight fragment packing ----------------
// K' layout for GEMM1 (288): [feats 0..23][zero 24..31][hi 32..159][hj 160..287]
__global__ __launch_bounds__(256) void prep_kernel(
    const float* __restrict__ h,
    const float* __restrict__ r_feat,
    const float* __restrict__ edge_feat,
    const float* __restrict__ ewW, const float* __restrict__ ewB,
    const float* __restrict__ kW1, const float* __restrict__ vW1,
    const float* __restrict__ kW2, const float* __restrict__ vW2,
    const float* __restrict__ qW1, const float* __restrict__ qW2,
    unsigned short* __restrict__ h_bf, unsigned short* __restrict__ feats_bf,
    float* __restrict__ ew_pre,
    unsigned short* __restrict__ w1p, unsigned short* __restrict__ w2p,
    unsigned short* __restrict__ w1q, unsigned short* __restrict__ w2q)
{
    const int b = blockIdx.x, t = threadIdx.x;
    if (b < 1000) {
        const int gid = b * 256 + t;
        const float4* hp = (const float4*)(h + (size_t)gid * 8);
        float4 a = hp[0], c = hp[1];
        ushort4 u0, u1;
        u0.x = f2bf(a.x); u0.y = f2bf(a.y); u0.z = f2bf(a.z); u0.w = f2bf(a.w);
        u1.x = f2bf(c.x); u1.y = f2bf(c.y); u1.z = f2bf(c.z); u1.w = f2bf(c.w);
        *(ushort4*)(h_bf + (size_t)gid * 8) = u0;
        *(ushort4*)(h_bf + (size_t)gid * 8 + 4) = u1;
    } else if (b < 2000) {
        const int e = (b - 1000) * 256 + t;
        float4 ef = *(const float4*)(edge_feat + (size_t)e * 4);
        float rf[20];
        #pragma unroll
        for (int i = 0; i < 5; ++i)
            *(float4*)&rf[i * 4] = *(const float4*)(r_feat + (size_t)e * 20 + i * 4);
        float z = ewB[0];
        #pragma unroll
        for (int i = 0; i < 20; ++i) z = fmaf(rf[i], ewW[i], z);
        ew_pre[e] = (1.f / (1.f + expf(-z))) * (1.f / 16.f);
        unsigned short fb[32];
        fb[0] = f2bf(ef.x); fb[1] = f2bf(ef.y); fb[2] = f2bf(ef.z); fb[3] = f2bf(ef.w);
        #pragma unroll
        for (int i = 0; i < 20; ++i) fb[4 + i] = f2bf(rf[i]);
        #pragma unroll
        for (int i = 24; i < 32; ++i) fb[i] = 0;
        #pragma unroll
        for (int i = 0; i < 4; ++i)
            *(int4*)(feats_bf + (size_t)e * 32 + i * 8) = *(int4*)&fb[i * 8];
    } else {
        const int idx = (b - 2000) * 256 + t;
        if (idx < 73728) {
            int j = idx & 7, l = (idx >> 3) & 63, mtc = (idx >> 9) & 15, s = idx >> 13;
            int kp = s * 32 + (l >> 4) * 8 + j;
            int col = mtc * 16 + (l & 15);
            float v = 0.f;
            int row = (kp < 24) ? kp : ((kp >= 32) ? (kp - 8) : -1);
            if (row >= 0) v = (col < 128) ? kW1[(size_t)row * 128 + col]
                                          : vW1[(size_t)row * 128 + col - 128];
            w1p[idx] = f2bf(v);
        } else if (idx < 92160) {
            int i2 = idx - 73728;
            int j = i2 & 7, l = (i2 >> 3) & 63, sc = i2 >> 9;
            int ct = sc % 9, s2 = sc / 9;
            int k = s2 * 32 + (l >> 4) * 8 + j;
            float v = (ct < 8) ? kW2[(size_t)k * 128 + ct * 16 + (l & 15)]
                               : vW2[(size_t)k * 16 + (l & 15)];
            w2p[i2] = f2bf(v);
        } else if (idx < 108544) {
            int i3 = idx - 92160;
            int j = i3 & 7, l = (i3 >> 3) & 63, mt = (i3 >> 9) & 7, s = i3 >> 12;
            int k = s * 32 + (l >> 4) * 8 + j;
            w1q[i3] = f2bf(qW1[(size_t)k * 128 + mt * 16 + (l & 15)]);
        } else if (idx < 124928) {
            int i4 = idx - 108544;
            int j = i4 & 7, l = (i4 >> 3) & 63, mt = (i4 >> 9) & 7, s = i4 >> 12;
            int k = s * 32 + (l >> 4) * 8 + j;
            w2q[i4] = f2bf(qW2[(size_t)k * 128 + mt * 16 + (l & 15)]);
        }
    }
}

// ---------------- Kernel A: q = MLP(h) via MFMA, 32 nodes/block ----------------
__global__ __launch_bounds__(256, 4) void qmlp_kernel(
    const unsigned short* __restrict__ h_bf,
    const float* __restrict__ B1, const float* __restrict__ G,
    const float* __restrict__ BE, const float* __restrict__ B2,
    const unsigned short* __restrict__ w1q, const unsigned short* __restrict__ w2q,
    float* __restrict__ qout)
{
    __shared__ __align__(16) unsigned char hsq[8192];   // 16 chunks x 32 nodes x 16B
    __shared__ float2 lnb[4][32];
    __shared__ float  gb1[128];
    __shared__ float2 gbe[128];
    __shared__ float  gb2[128];

    const int t = threadIdx.x;
    const int nb = blockIdx.x * 32;
    const int wc = t >> 6, l = t & 63, lrow = l & 15, lgrp = l >> 4;

    if (t < 128) { gb1[t] = B1[t]; gbe[t] = make_float2(G[t], BE[t]); gb2[t] = B2[t]; }

    unsigned offN[2];
    #pragma unroll
    for (int nt = 0; nt < 2; ++nt)
        offN[nt] = (unsigned)(nb + nt * 16 + lrow) * 128 + lgrp * 8;
    __syncthreads();

    // GEMM1: 128 cols (wave: 2 mt), 32 nodes (2 nt), K=128 (4 steps), depth-2
    f32x4 acc1[2][2];
    #pragma unroll
    for (int mt = 0; mt < 2; ++mt) {
        const int cb = wc * 32 + mt * 16 + lgrp * 4;
        #pragma unroll
        for (int nt = 0; nt < 2; ++nt) {
            acc1[mt][nt][0] = gb1[cb];     acc1[mt][nt][1] = gb1[cb + 1];
            acc1[mt][nt][2] = gb1[cb + 2]; acc1[mt][nt][3] = gb1[cb + 3];
        }
    }
    {
        auto ldA = [&](int s, bf16x8* dst) {
            #pragma unroll
            for (int mt = 0; mt < 2; ++mt)
                dst[mt] = *(const bf16x8*)(w1q + (size_t)((s * 8 + wc * 2 + mt) * 64 + l) * 8);
        };
        auto ldB = [&](int s, bf16x8* dst) {
            #pragma unroll
            for (int nt = 0; nt < 2; ++nt)
                dst[nt] = *(const bf16x8*)(h_bf + offN[nt] + s * 32);
        };
        bf16x8 aB[2][2], bB[2][2];
        ldA(0, aB[0]); ldB(0, bB[0]);
        ldA(1, aB[1]); ldB(1, bB[1]);
        #pragma unroll
        for (int s = 0; s < 4; ++s) {
            const int c = s & 1;
            #pragma unroll
            for (int mt = 0; mt < 2; ++mt)
                #pragma unroll
                for (int nt = 0; nt < 2; ++nt)
                    acc1[mt][nt] = __builtin_amdgcn_mfma_f32_16x16x32_bf16(aB[c][mt], bB[c][nt], acc1[mt][nt], 0, 0, 0);
            if (s < 2) { ldA(s + 2, aB[c]); ldB(s + 2, bB[c]); }
        }
    }

    // LN partials: this wave's 32 cols
    float2 myln[2];
    #pragma unroll
    for (int nt = 0; nt < 2; ++nt) {
        float p1 = 0.f, p2 = 0.f;
        #pragma unroll
        for (int mt = 0; mt < 2; ++mt)
            #pragma unroll
            for (int r = 0; r < 4; ++r) { float v = acc1[mt][nt][r]; p1 += v; p2 += v * v; }
        p1 += __shfl_xor(p1, 16); p2 += __shfl_xor(p2, 16);
        p1 += __shfl_xor(p1, 32); p2 += __shfl_xor(p2, 32);
        myln[nt] = make_float2(p1, p2);
        if (l < 16) lnb[wc][nt * 16 + l] = myln[nt];
    }
    __syncthreads();

    // normalize + ReLU + bf16 -> hsq (fragment-native layout)
    #pragma unroll
    for (int nt = 0; nt < 2; ++nt) {
        const int el = nt * 16 + lrow;
        float2 a0 = lnb[0][el], a1 = lnb[1][el], a2 = lnb[2][el], a3 = lnb[3][el];
        const float s1 = a0.x + a1.x + a2.x + a3.x;
        const float s2 = a0.y + a1.y + a2.y + a3.y;
        const float mu = s1 * (1.f / 128.f);
        const float rs = rsqrtf(s2 * (1.f / 128.f) - mu * mu + LN_EPS);
        #pragma unroll
        for (int mt = 0; mt < 2; ++mt) {
            const int cb = wc * 32 + mt * 16 + lgrp * 4;
            const float2 g0 = gbe[cb], g1 = gbe[cb+1], g2 = gbe[cb+2], g3 = gbe[cb+3];
            ushort4 u;
            u.x = f2bf(fmaxf((acc1[mt][nt][0] - mu) * rs * g0.x + g0.y, 0.f));
            u.y = f2bf(fmaxf((acc1[mt][nt][1] - mu) * rs * g1.x + g1.y, 0.f));
            u.z = f2bf(fmaxf((acc1[mt][nt][2] - mu) * rs * g2.x + g2.y, 0.f));
            u.w = f2bf(fmaxf((acc1[mt][nt][3] - mu) * rs * g3.x + g3.y, 0.f));
            *(ushort4*)(hsq + ((cb >> 3) * 32 + el) * 16 + (lgrp & 1) * 8) = u;
        }
    }
    __syncthreads();

    // GEMM2: 128 cols, K=128
    f32x4 acc2[2][2];
    #pragma unroll
    for (int km = 0; km < 2; ++km) {
        const int c2 = (wc * 2 + km) * 16 + lgrp * 4;
        #pragma unroll
        for (int nt = 0; nt < 2; ++nt) {
            acc2[km][nt][0] = gb2[c2];     acc2[km][nt][1] = gb2[c2 + 1];
            acc2[km][nt][2] = gb2[c2 + 2]; acc2[km][nt][3] = gb2[c2 + 3];
        }
    }
    {
        bf16x8 a0C = *(const bf16x8*)(w2q + (size_t)((wc * 2) * 64 + l) * 8);
        bf16x8 a1C = *(const bf16x8*)(w2q + (size_t)((wc * 2 + 1) * 64 + l) * 8);
        #pragma unroll
        for (int s2 = 0; s2 < 4; ++s2) {
            bf16x8 a0N, a1N;
            if (s2 < 3) {
                a0N = *(const bf16x8*)(w2q + (size_t)(((s2+1) * 8 + wc * 2) * 64 + l) * 8);
                a1N = *(const bf16x8*)(w2q + (size_t)(((s2+1) * 8 + wc * 2 + 1) * 64 + l) * 8);
            }
            bf16x8 hb[2];
            #pragma unroll
            for (int nt = 0; nt < 2; ++nt)
                hb[nt] = *(const bf16x8*)(hsq + (((s2 * 4 + lgrp) * 32) + nt * 16 + lrow) * 16);
            #pragma unroll
            for (int nt = 0; nt < 2; ++nt) {
                acc2[0][nt] = __builtin_amdgcn_mfma_f32_16x16x32_bf16(a0C, hb[nt], acc2[0][nt], 0, 0, 0);
                acc2[1][nt] = __builtin_amdgcn_mfma_f32_16x16x32_bf16(a1C, hb[nt], acc2[1][nt], 0, 0, 0);
            }
            a0C = a0N; a1C = a1N;
        }
    }
    #pragma unroll
    for (int km = 0; km < 2; ++km) {
        const int c2 = (wc * 2 + km) * 16 + lgrp * 4;
        #pragma unroll
        for (int nt = 0; nt < 2; ++nt) {
            const int el = nt * 16 + lrow;
            float4 o;
            o.x = acc2[km][nt][0]; o.y = acc2[km][nt][1];
            o.z = acc2[km][nt][2]; o.w = acc2[km][nt][3];
            *(float4*)(qout + (size_t)(nb + el) * 128 + c2) = o;
        }
    }
}

// ------------- Kernel B: MFMA edge kernel, 32 edges/block, depth-2 pipeline -------------
__global__ __launch_bounds__(256, 4) void edge_kernel(
    const unsigned short* __restrict__ h_bf,
    const unsigned short* __restrict__ feats_bf,
    const int*   __restrict__ eidx,
    const float* __restrict__ ew_pre,
    const float* __restrict__ kB1, const float* __restrict__ kG, const float* __restrict__ kBE,
    const float* __restrict__ vB1, const float* __restrict__ vG, const float* __restrict__ vBE,
    const float* __restrict__ kB2, const float* __restrict__ vB2,
    const unsigned short* __restrict__ w1p, const unsigned short* __restrict__ w2p,
    const float* __restrict__ q,
    float* __restrict__ ex_out, float* __restrict__ vw_out, float* __restrict__ denom)
{
    __shared__ __align__(16) unsigned char hs[16384];  // 2 regions x 16 chunks x 32 e x 16B
    __shared__ float2 lnb[4][32];
    __shared__ float  gb1[256];
    __shared__ float2 gbe[256];
    __shared__ float  gb2[144];
    __shared__ int    dst_sh[32];
    __shared__ float  ew_s[32];

    const int t = threadIdx.x;
    const int eb = blockIdx.x * 32;
    const int wc = t >> 6, l = t & 63, lrow = l & 15, lgrp = l >> 4;

    gb1[t] = (t < 128) ? kB1[t] : vB1[t - 128];
    gbe[t] = make_float2((t < 128) ? kG[t] : vG[t - 128],
                         (t < 128) ? kBE[t] : vBE[t - 128]);
    if (t < 144) gb2[t] = (t < 128) ? kB2[t] : vB2[t - 128];
    if (t < 32) {
        dst_sh[t] = eidx[NE + eb + t];
        ew_s[t]   = ew_pre[eb + t];
    }

    unsigned offF[2], offD[2], offS[2];
    #pragma unroll
    for (int nt = 0; nt < 2; ++nt) {
        const int e = eb + nt * 16 + lrow;
        offF[nt] = (unsigned)e * 32 + lgrp * 8;
        offD[nt] = (unsigned)eidx[NE + e] * 128 + lgrp * 8;
        offS[nt] = (unsigned)eidx[e] * 128 + lgrp * 8;
    }
    __syncthreads();

    // ---- GEMM1: hiddenT[256 cols][32 e], K'=288 (9 steps), depth-2 pipeline ----
    f32x4 acc1[4][2];
    #pragma unroll
    for (int mt = 0; mt < 4; ++mt) {
        const int cb = wc * 64 + mt * 16 + lgrp * 4;
        #pragma unroll
        for (int nt = 0; nt < 2; ++nt) {
            acc1[mt][nt][0] = gb1[cb];     acc1[mt][nt][1] = gb1[cb + 1];
            acc1[mt][nt][2] = gb1[cb + 2]; acc1[mt][nt][3] = gb1[cb + 3];
        }
    }
    {
        auto ldA = [&](int s, bf16x8* dst) {
            #pragma unroll
            for (int mt = 0; mt < 4; ++mt)
                dst[mt] = *(const bf16x8*)(w1p + (size_t)((s * 16 + wc * 4 + mt) * 64 + l) * 8);
        };
        auto ldB = [&](int s, bf16x8* dst) {
            #pragma unroll
            for (int nt = 0; nt < 2; ++nt) {
                const unsigned short* p = (s == 0) ? (feats_bf + offF[nt])
                                        : (s <= 4) ? (h_bf + offD[nt] + (s - 1) * 32)
                                                   : (h_bf + offS[nt] + (s - 5) * 32);
                dst[nt] = *(const bf16x8*)p;
            }
        };
        bf16x8 aB[2][4], bB[2][2];
        ldA(0, aB[0]); ldB(0, bB[0]);
        ldA(1, aB[1]); ldB(1, bB[1]);
        #pragma unroll
        for (int s = 0; s < 9; ++s) {
            const int c = s & 1;
            #pragma unroll
            for (int mt = 0; mt < 4; ++mt)
                #pragma unroll
                for (int nt = 0; nt < 2; ++nt)
                    acc1[mt][nt] = __builtin_amdgcn_mfma_f32_16x16x32_bf16(aB[c][mt], bB[c][nt], acc1[mt][nt], 0, 0, 0);
            if (s < 7) { ldA(s + 2, aB[c]); ldB(s + 2, bB[c]); }
        }
    }

    // ---- LN partials (per edge, this wave's 64 cols) ----
    float2 myln[2];
    #pragma unroll
    for (int nt = 0; nt < 2; ++nt) {
        float p1 = 0.f, p2 = 0.f;
        #pragma unroll
        for (int mt = 0; mt < 4; ++mt)
            #pragma unroll
            for (int r = 0; r < 4; ++r) { float v = acc1[mt][nt][r]; p1 += v; p2 += v * v; }
        p1 += __shfl_xor(p1, 16); p2 += __shfl_xor(p2, 16);
        p1 += __shfl_xor(p1, 32); p2 += __shfl_xor(p2, 32);
        myln[nt] = make_float2(p1, p2);
        if (l < 16) lnb[wc][nt * 16 + l] = myln[nt];
    }
    __syncthreads();   // B1

    // ---- normalize + ReLU + bf16 -> hs (fragment-native: [region][k>>3][edge][8]) ----
    #pragma unroll
    for (int nt = 0; nt < 2; ++nt) {
        const int el = nt * 16 + lrow;
        const float2 oth = lnb[wc ^ 1][el];
        const float s1 = myln[nt].x + oth.x, s2 = myln[nt].y + oth.y;
        const float mu = s1 * (1.f / 128.f);
        const float rs = rsqrtf(s2 * (1.f / 128.f) - mu * mu + LN_EPS);
        #pragma unroll
        for (int mt = 0; mt < 4; ++mt) {
            const int cb = wc * 64 + mt * 16 + lgrp * 4;
            const int region = cb >> 7, kc = cb & 127;
            const float2 g0 = gbe[cb], g1 = gbe[cb+1], g2 = gbe[cb+2], g3 = gbe[cb+3];
            ushort4 u;
            u.x = f2bf(fmaxf((acc1[mt][nt][0] - mu) * rs * g0.x + g0.y, 0.f));
            u.y = f2bf(fmaxf((acc1[mt][nt][1] - mu) * rs * g1.x + g1.y, 0.f));
            u.z = f2bf(fmaxf((acc1[mt][nt][2] - mu) * rs * g2.x + g2.y, 0.f));
            u.w = f2bf(fmaxf((acc1[mt][nt][3] - mu) * rs * g3.x + g3.y, 0.f));
            *(ushort4*)(hs + region * 8192 + ((kc >> 3) * 32 + el) * 16 + (lgrp & 1) * 8) = u;
        }
    }
    __syncthreads();   // B2

    // ---- GEMM2: kT[128][32e] + vT[16][32e], K=128 (4 steps) ----
    f32x4 acc2[2][2], accv;
    #pragma unroll
    for (int km = 0; km < 2; ++km) {
        const int c0 = (wc * 2 + km) * 16 + lgrp * 4;
        #pragma unroll
        for (int nt = 0; nt < 2; ++nt) {
            acc2[km][nt][0] = gb2[c0];     acc2[km][nt][1] = gb2[c0 + 1];
            acc2[km][nt][2] = gb2[c0 + 2]; acc2[km][nt][3] = gb2[c0 + 3];
        }
    }
    const int vel = wc * 16 + lrow;   // valid when wc<2
    {
        const int cv = 128 + lgrp * 4;
        accv[0] = gb2[cv]; accv[1] = gb2[cv+1]; accv[2] = gb2[cv+2]; accv[3] = gb2[cv+3];
    }
    {
        bf16x8 a0C = *(const bf16x8*)(w2p + (size_t)((wc * 2) * 64 + l) * 8);
        bf16x8 a1C = *(const bf16x8*)(w2p + (size_t)((wc * 2 + 1) * 64 + l) * 8);
        bf16x8 avC = *(const bf16x8*)(w2p + (size_t)(8 * 64 + l) * 8);
        #pragma unroll
        for (int s2 = 0; s2 < 4; ++s2) {
            bf16x8 a0N, a1N, avN;
            if (s2 < 3) {
                a0N = *(const bf16x8*)(w2p + (size_t)(((s2+1) * 9 + wc * 2) * 64 + l) * 8);
                a1N = *(const bf16x8*)(w2p + (size_t)(((s2+1) * 9 + wc * 2 + 1) * 64 + l) * 8);
                avN = *(const bf16x8*)(w2p + (size_t)(((s2+1) * 9 + 8) * 64 + l) * 8);
            }
            bf16x8 hb[2];
            #pragma unroll
            for (int nt = 0; nt < 2; ++nt)
                hb[nt] = *(const bf16x8*)(hs + ((s2 * 4 + lgrp) * 32 + nt * 16 + lrow) * 16);
            #pragma unroll
            for (int nt = 0; nt < 2; ++nt) {
                acc2[0][nt] = __builtin_amdgcn_mfma_f32_16x16x32_bf16(a0C, hb[nt], acc2[0][nt], 0, 0, 0);
                acc2[1][nt] = __builtin_amdgcn_mfma_f32_16x16x32_bf16(a1C, hb[nt], acc2[1][nt], 0, 0, 0);
            }
            if (wc < 2) {
                bf16x8 hv = *(const bf16x8*)(hs + 8192 + ((s2 * 4 + lgrp) * 32 + vel) * 16);
                accv = __builtin_amdgcn_mfma_f32_16x16x32_bf16(avC, hv, accv, 0, 0, 0);
            }
            a0C = a0N; a1C = a1N; avC = avN;
        }
    }

    // ---- v output ----
    if (wc < 2) {
        const float sc = ew_s[vel];
        float4 vo;
        vo.x = accv[0] * sc; vo.y = accv[1] * sc; vo.z = accv[2] * sc; vo.w = accv[3] * sc;
        *(float4*)(vw_out + (size_t)(eb + vel) * 16 + lgrp * 4) = vo;
    }

    // ---- scores + exp + denom atomics ----
    #pragma unroll
    for (int km = 0; km < 2; ++km) {
        #pragma unroll
        for (int nt = 0; nt < 2; ++nt) {
            const int el = nt * 16 + lrow;
            const int c0 = (wc * 2 + km) * 16 + lgrp * 4;
            const int dst = dst_sh[el];
            const float4 qv = *(const float4*)(q + (size_t)dst * 128 + c0);
            float sp = acc2[km][nt][0] * qv.x + acc2[km][nt][1] * qv.y
                     + acc2[km][nt][2] * qv.z + acc2[km][nt][3] * qv.w;
            sp += __shfl_xor(sp, 16);
            if ((l & 16) == 0) {
                const float exv = expf(sp * INV_SQRT_HD);
                const int hh = (wc * 2 + km) * 2 + (lgrp >> 1);
                ex_out[(size_t)(eb + el) * 16 + hh] = exv;
                atomicAdd(&denom[(size_t)dst * 16 + hh], exv);
            }
        }
    }
}

// ------------- Kernel C: alpha = ex/denom, scatter out += sum_h(alpha*vw)*rel_x -------------
__global__ __launch_bounds__(256) void finalize_kernel(
    const int* __restrict__ eidx, const float* __restrict__ relx,
    const float* __restrict__ exb, const float* __restrict__ vwb,
    const float* __restrict__ den, float* __restrict__ out)
{
    const int e = blockIdx.x * 256 + threadIdx.x;
    const int dst = eidx[NE + e];
    const float4* ex4 = (const float4*)(exb + (size_t)e*16);
    const float4* vw4 = (const float4*)(vwb + (size_t)e*16);
    const float4* dn4 = (const float4*)(den + (size_t)dst*16);
    float s = 0.f;
    #pragma unroll
    for (int k = 0; k < 4; ++k) {
        float4 a = ex4[k], b = vw4[k], d = dn4[k];
        s += (a.x/d.x)*b.x + (a.y/d.y)*b.y + (a.z/d.z)*b.z + (a.w/d.w)*b.w;
    }
    float r0 = relx[(size_t)e*3+0], r1 = relx[(size_t)e*3+1], r2 = relx[(size_t)e*3+2];
    atomicAdd(&out[(size_t)dst*3+0], s*r0);
    atomicAdd(&out[(size_t)dst*3+1], s*r1);
    atomicAdd(&out[(size_t)dst*3+2], s*r2);
}

extern "C" void kernel_launch(void* const* d_in, const int* in_sizes, int n_in,
                              void* d_out, int out_size, void* d_ws, size_t ws_size,
                              hipStream_t stream) {
    const float* h         = (const float*)d_in[0];
    const float* rel_x     = (const float*)d_in[1];
    const float* r_feat    = (const float*)d_in[2];
    const float* edge_feat = (const float*)d_in[3];
    const int*   eidx      = (const int*)  d_in[4];
    const float* kW1 = (const float*)d_in[5];
    const float* kB1 = (const float*)d_in[6];
    const float* kG  = (const float*)d_in[7];
    const float* kBE = (const float*)d_in[8];
    const float* kW2 = (const float*)d_in[9];
    const float* kB2 = (const float*)d_in[10];
    const float* vW1 = (const float*)d_in[11];
    const float* vB1 = (const float*)d_in[12];
    const float* vG  = (const float*)d_in[13];
    const float* vBE = (const float*)d_in[14];
    const float* vW2 = (const float*)d_in[15];
    const float* vB2 = (const float*)d_in[16];
    const float* qW1 = (const float*)d_in[17];
    const float* qB1 = (const float*)d_in[18];
    const float* qG  = (const float*)d_in[19];
    const float* qBE = (const float*)d_in[20];
    const float* qW2 = (const float*)d_in[21];
    const float* qB2 = (const float*)d_in[22];
    const float* ewW = (const float*)d_in[23];
    const float* ewB = (const float*)d_in[24];

    float* ws   = (float*)d_ws;
    float* qbuf = ws;                             // N*128
    float* exb  = qbuf + (size_t)NN*128;          // E*16
    float* vwb  = exb + (size_t)NE*16;            // E*16
    float* den  = vwb + (size_t)NE*16;            // N*16
    float* ewp  = den + (size_t)NN*16;            // E
    unsigned short* w1p  = (unsigned short*)(ewp + (size_t)NE);   // 73728
    unsigned short* w2p  = w1p + 73728;                           // 18432
    unsigned short* w1q  = w2p + 18432;                           // 16384
    unsigned short* w2q  = w1q + 16384;                           // 16384
    unsigned short* h_bf = w2q + 16384;                           // N*128
    unsigned short* feats_bf = h_bf + (size_t)NN*128;             // E*32
    float* outf = (float*)d_out;

    hipMemsetAsync(den, 0, (size_t)NN*16*sizeof(float), stream);
    hipMemsetAsync(outf, 0, (size_t)NN*3*sizeof(float), stream);

    prep_kernel<<<2488, 256, 0, stream>>>(h, r_feat, edge_feat, ewW, ewB,
                                          kW1, vW1, kW2, vW2, qW1, qW2,
                                          h_bf, feats_bf, ewp, w1p, w2p, w1q, w2q);
    qmlp_kernel<<<NN/32, 256, 0, stream>>>(h_bf, qB1, qG, qBE, qB2, w1q, w2q, qbuf);
    edge_kernel<<<NE/32, 256, 0, stream>>>(h_bf, feats_bf, eidx, ewp,
                                           kB1, kG, kBE, vB1, vG, vBE,
                                           kB2, vB2, w1p, w2p, qbuf,
                                           exb, vwb, den);
    finalize_kernel<<<NE/256, 256, 0, stream>>>(eidx, rel_x, exb, vwb, den, outf);
}